// Round 11
// baseline (2165.520 us; speedup 1.0000x reference)
//
#include <hip/hip_runtime.h>

// RNN_16492674416646: h_t = tanh(x_t W_ih^T + b_ih + b_hh + h_{t-1} W_hh^T),
// out_t = h_t W_out^T + b_out. T=2048, B=128, IN=2, H=200, OUT=1, fp32.
//
// R11 = R10 (MFMA split-bf16) + two fixes:
// 1) Bank-disjoint h ring: ring[8][2][224] ushort. lo offset within slot =
//    448 B = 64 mod 128 -> lo chunks use banks 16-31 while hi use 0-15 (and
//    flip together with kt's 64B stride): the wave's 8 distinct 16B chunks
//    cover 32 distinct banks -> conflict-free. (R10: hlo 3584 B after hhi,
//    3584 mod 128 = 0 -> same banks -> 5.87e7 conflict cycles, 224 cyc/step.)
// 2) 4 waves (256 thr, 1 wave/SIMD): per-wave A-read count is fixed at 7,
//    so halving waves halves LDS A-traffic (56 -> 28 ds_read_b128/step).
//    Wave w owns n-tiles {w+4i}: w0 gets 4 tiles, w1..w3 get 3 (13 total).
//    B-fragments ~224 reg-equiv/wave fit the 1-wave/SIMD budget (512);
//    AGPR parking is free (MFMA reads AGPRs natively).
// Precision: split-bf16. A row0 = h_hi, row1 = h_lo; B terms W_hi, W_lo;
// y = sum of D rows 0,1 over both terms = (W_hi+W_lo)(h_hi+h_lo).
// One barrier/step; head drained from the 8-slot ring every 8 steps.

typedef short s8v __attribute__((ext_vector_type(8)));   // 8 x bf16 bits
typedef float f4v __attribute__((ext_vector_type(4)));

static constexpr int T = 2048;
static constexpr int B = 128;
static constexpr int H = 200;
static constexpr int NTHR = 256;
static constexpr int KT = 7;     // k-tiles of 32
static constexpr int HP = 224;   // padded H

__device__ __forceinline__ unsigned short f2bf(float f) {
    unsigned int u = __float_as_uint(f);            // RNE to bf16
    unsigned int r = (u + 0x7FFFu + ((u >> 16) & 1u)) >> 16;
    return (unsigned short)r;
}
__device__ __forceinline__ float bf2f(unsigned short h) {
    return __uint_as_float(((unsigned int)h) << 16);
}

__global__ __attribute__((amdgpu_flat_work_group_size(NTHR, NTHR),
                          amdgpu_waves_per_eu(1, 1)))
void rnn_fused(const float* __restrict__ x,     // [T,B,2]
               const float* __restrict__ W_ih,  // [H,2]
               const float* __restrict__ W_hh,  // [H,H]
               const float* __restrict__ b_ih,  // [H]
               const float* __restrict__ b_hh,  // [H]
               const float* __restrict__ W_out, // [1,H]
               const float* __restrict__ b_out, // [1]
               float* __restrict__ out)         // [T,B]
{
    const int b    = blockIdx.x;
    const int tid  = threadIdx.x;
    const int w    = tid >> 6;       // wave id 0..3
    const int lane = tid & 63;
    const int m    = lane & 15;      // A-row / B-col / D-col
    const int q    = lane >> 4;      // k-quad

    // h ring: [slot][hi/lo][col]. See header for bank layout proof.
    __shared__ __align__(16) unsigned short ring[8][2][HP];
    __shared__ float xs[2 * T];                          // x column (16 KB)

    for (int i = tid; i < 8 * 2 * HP; i += NTHR) (&ring[0][0][0])[i] = 0;
    for (int idx = tid; idx < T; idx += NTHR) {
        const float2 v = *(const float2*)(x + (size_t)idx * (B * 2) + 2 * b);
        xs[2 * idx] = v.x; xs[2 * idx + 1] = v.y;
    }

    // --- loop-invariant B-fragments: tile i -> cols 16*(w+4i)+m ---
    const int nt[4] = {16 * w + m, 16 * (w + 4) + m,
                       16 * (w + 8) + m, 16 * (w + 12) + m};
    const bool hasT[4] = {true, true, true, (w == 0)};
    s8v Bh[4][KT], Bl[4][KT];
#pragma unroll
    for (int i = 0; i < 4; ++i) {
#pragma unroll
        for (int kt = 0; kt < KT; ++kt) {
            s8v bh{}, bl{};
            if (hasT[i] && nt[i] < H) {
#pragma unroll
                for (int j = 0; j < 8; ++j) {
                    const int ks = 32 * kt + 8 * q + j;
                    const float wv = (ks < H) ? W_hh[nt[i] * H + ks] : 0.f;
                    const unsigned short hi = f2bf(wv);
                    bh[j] = (short)hi;
                    bl[j] = (short)f2bf(wv - bf2f(hi));
                }
            }
            Bh[i][kt] = bh; Bl[i][kt] = bl;
        }
    }

    // --- epilogue constants per tile (q==0 lanes own col nt[i]) ---
    float wx0[4], wx1[4], bsum[4];
#pragma unroll
    for (int i = 0; i < 4; ++i) {
        const bool v = (q == 0) && hasT[i] && nt[i] < H;
        wx0[i]  = v ? W_ih[nt[i] * 2]     : 0.f;
        wx1[i]  = v ? W_ih[nt[i] * 2 + 1] : 0.f;
        bsum[i] = v ? (b_ih[nt[i]] + b_hh[nt[i]]) : 0.f;
    }
    // --- head constants ---
    const float wo0 = W_out[lane];
    const float wo1 = W_out[64 + lane];
    const float wo2 = W_out[128 + lane];
    const float wo3 = (192 + lane < H) ? W_out[192 + lane] : 0.f;
    const float bo  = b_out[0];

    __syncthreads();

    float* op = out + b;

    auto drain = [&](int slot, int tout) {
        float v = (bf2f(ring[slot][0][lane])     + bf2f(ring[slot][1][lane]))     * wo0
                + (bf2f(ring[slot][0][64+lane])  + bf2f(ring[slot][1][64+lane]))  * wo1
                + (bf2f(ring[slot][0][128+lane]) + bf2f(ring[slot][1][128+lane])) * wo2;
        if (lane < 32)   // cols 192..223; pads zero, wo3 zero past 199
            v += (bf2f(ring[slot][0][192+lane]) + bf2f(ring[slot][1][192+lane])) * wo3;
#pragma unroll
        for (int off = 32; off > 0; off >>= 1)
            v += __shfl_down(v, off, 64);
        if (lane == 0) op[(size_t)tout * B] = v + bo;
    };

    for (int t = 0; t < T; ++t) {
        const float x0 = xs[2 * t], x1 = xs[2 * t + 1];
        const int sr = (t + 7) & 7;             // read slot (h_{t-1})
        const int sw = t & 7;                   // write slot (h_t)

        // A source: row 0 <- hi, row 1 <- lo, rows 2..15 broadcast row 0's
        // address. One vaddr + 7 immediate-offset ds_read_b128.
        const unsigned short* lp = &ring[sr][(m == 1) ? 1 : 0][8 * q];
        s8v A[KT];
#pragma unroll
        for (int kt = 0; kt < KT; ++kt) A[kt] = *(const s8v*)(lp + 32 * kt);

        f4v acch[4], accl[4];
#pragma unroll
        for (int i = 0; i < 4; ++i) { acch[i] = f4v{0,0,0,0}; accl[i] = f4v{0,0,0,0}; }
#pragma unroll
        for (int i = 0; i < 4; ++i) {
            if (hasT[i]) {
#pragma unroll
                for (int kt = 0; kt < KT; ++kt) {
                    acch[i] = __builtin_amdgcn_mfma_f32_16x16x32_bf16(A[kt], Bh[i][kt], acch[i], 0, 0, 0);
                    accl[i] = __builtin_amdgcn_mfma_f32_16x16x32_bf16(A[kt], Bl[i][kt], accl[i], 0, 0, 0);
                }
            }
        }

        // --- epilogue: q==0 lanes hold D rows 0,1 for col nt[i] ---
        if (q == 0) {
#pragma unroll
            for (int i = 0; i < 4; ++i) {
                if (hasT[i] && nt[i] < H) {
                    const float y   = (acch[i][0] + acch[i][1])
                                    + (accl[i][0] + accl[i][1]);
                    const float pre = y + fmaf(x0, wx0[i], fmaf(x1, wx1[i], bsum[i]));
                    const float e   = __expf(2.f * pre);     // tanh via exp
                    const float th  = 1.f - 2.f / (e + 1.f);
                    const unsigned short hi = f2bf(th);
                    ring[sw][0][nt[i]] = hi;
                    ring[sw][1][nt[i]] = f2bf(th - bf2f(hi));
                }
            }
        }

        // --- head: every 8 steps. slots 0..6 stable pre-barrier; slot 7
        // drained post-barrier by wave 3 (next rewrite is 8 barriers away).
        const bool dr = ((t & 7) == 7);
        if (dr) {
            drain(w, t - 7 + w);
            if (w < 3) drain(w + 4, t - 3 + w);
        }
        __syncthreads();
        if (dr && w == 3) drain(7, t);
    }
}

extern "C" void kernel_launch(void* const* d_in, const int* in_sizes, int n_in,
                              void* d_out, int out_size, void* d_ws, size_t ws_size,
                              hipStream_t stream) {
    const float* x     = (const float*)d_in[0];
    const float* W_ih  = (const float*)d_in[1];
    const float* W_hh  = (const float*)d_in[2];
    const float* b_ih  = (const float*)d_in[3];
    const float* b_hh  = (const float*)d_in[4];
    const float* W_out = (const float*)d_in[5];
    const float* b_out = (const float*)d_in[6];
    float* out = (float*)d_out;

    rnn_fused<<<B, NTHR, 0, stream>>>(x, W_ih, W_hh, b_ih, b_hh, W_out, b_out, out);
}

// Round 12
// 1371.764 us; speedup vs baseline: 1.5786x; 1.5786x over previous
//
#include <hip/hip_runtime.h>
#include <hip/hip_fp16.h>

// RNN_16492674416646: h_t = tanh(x_t W_ih^T + b_ih + b_hh + h_{t-1} W_hh^T),
// out_t = h_t W_out^T + b_out. T=2048, B=128, IN=2, H=200, OUT=1, fp32.
//
// R12. Evidence so far: allocator keeps only ~110-130 arch VGPRs resident;
// LLVM requires VGPR-class A/B for MFMA, so any parked fragment costs
// accvgpr copies per use (R11: ~400 VALU/wave/step, 2538 cyc/step).
// Design to fit: 8 MFMA waves (2/SIMD), each wave owns tile w and tile 8+w
// (tiles 13..15 are all-pad) -> 14 s8v B-frags = 56 regs + A 28 + acc 8.
// Precision: W as SINGLE fp16 term (rel 2^-12); h split fp16 hi+lo on A
// rows 0/1 -> y = W(h_hi + h_lo) = acc[0]+acc[1]. 91 real MFMAs/step.
// Bank-disjoint ring (R11-verified, 0 conflicts): hi->lo offset 448 B
// = 64 mod 128. Ring is 9 deep: drain slot never collides with the write
// slot mid-loop; drain every 9 steps + barrier on drain iters only.
// Epilogue inline on q==0 lanes (offload costs an extra barrier+LDS
// roundtrip ~180 cyc > inline ~65).

typedef short s8v __attribute__((ext_vector_type(8)));   // 8 x fp16 bits
typedef float f4v __attribute__((ext_vector_type(4)));

static constexpr int T = 2048;
static constexpr int B = 128;
static constexpr int H = 200;
static constexpr int NTHR = 512;
static constexpr int KT = 7;     // k-tiles of 32 (224 padded)
static constexpr int HP = 224;   // padded H
static constexpr int RS = 9;     // ring slots

__device__ __forceinline__ unsigned short f2h(float f) {
    const __half h = __float2half_rn(f);
    return *(const unsigned short*)&h;
}
__device__ __forceinline__ float h2f(unsigned short u) {
    const __half h = *(const __half*)&u;
    return __half2float(h);
}

__global__ __attribute__((amdgpu_flat_work_group_size(NTHR, NTHR),
                          amdgpu_waves_per_eu(2, 2)))
void rnn_fused(const float* __restrict__ x,     // [T,B,2]
               const float* __restrict__ W_ih,  // [H,2]
               const float* __restrict__ W_hh,  // [H,H]
               const float* __restrict__ b_ih,  // [H]
               const float* __restrict__ b_hh,  // [H]
               const float* __restrict__ W_out, // [1,H]
               const float* __restrict__ b_out, // [1]
               float* __restrict__ out)         // [T,B]
{
    const int b    = blockIdx.x;
    const int tid  = threadIdx.x;
    const int w    = tid >> 6;       // wave id 0..7
    const int lane = tid & 63;
    const int m    = lane & 15;      // A-row sel / B-col / D-col
    const int q    = lane >> 4;      // k-quad

    // ring[slot][hi=0/lo=1][col]; lo offset 448 B = 64 mod 128 -> the wave's
    // 8 distinct 16B A-chunks hit 32 distinct banks (verified conflict-free).
    __shared__ __align__(16) unsigned short ring[RS][2][HP];
    __shared__ float xs[2 * T];      // x column (16 KB)

    for (int i = tid; i < RS * 2 * HP; i += NTHR) (&ring[0][0][0])[i] = 0;
    for (int idx = tid; idx < T; idx += NTHR) {
        const float2 v = *(const float2*)(x + (size_t)idx * (B * 2) + 2 * b);
        xs[2 * idx] = v.x; xs[2 * idx + 1] = v.y;
    }

    // --- loop-invariant B-fragments (fp16): tileA = w, tileB = 8+w ---
    const int nA = 16 * w + m;          // < 128, always valid
    const int nB = 128 + 16 * w + m;    // >= 200 for w >= 5 -> all-zero tile
    s8v BA[KT], BB[KT];
#pragma unroll
    for (int kt = 0; kt < KT; ++kt) {
        s8v ba{}, bb{};
#pragma unroll
        for (int j = 0; j < 8; ++j) {
            const int ks = 32 * kt + 8 * q + j;
            ba[j] = (short)((ks < H) ? f2h(W_hh[nA * H + ks]) : (unsigned short)0);
            bb[j] = (short)((nB < H && ks < H) ? f2h(W_hh[nB * H + ks])
                                               : (unsigned short)0);
        }
        BA[kt] = ba; BB[kt] = bb;
    }

    // --- epilogue constants (q==0 lanes own cols nA, nB) ---
    const float wxA0 = W_ih[nA * 2], wxA1 = W_ih[nA * 2 + 1];
    const float bA   = b_ih[nA] + b_hh[nA];
    const bool  vB   = (nB < H);
    const float wxB0 = vB ? W_ih[nB * 2]     : 0.f;
    const float wxB1 = vB ? W_ih[nB * 2 + 1] : 0.f;
    const float bB   = vB ? (b_ih[nB] + b_hh[nB]) : 0.f;

    // --- head constants ---
    const float wo0 = W_out[lane];
    const float wo1 = W_out[64 + lane];
    const float wo2 = W_out[128 + lane];
    const float wo3 = (192 + lane < H) ? W_out[192 + lane] : 0.f;
    const float bo  = b_out[0];

    __syncthreads();

    float* op = out + b;

    auto drain = [&](int slot, int tout) {
        float v = (h2f(ring[slot][0][lane])     + h2f(ring[slot][1][lane]))     * wo0
                + (h2f(ring[slot][0][64+lane])  + h2f(ring[slot][1][64+lane]))  * wo1
                + (h2f(ring[slot][0][128+lane]) + h2f(ring[slot][1][128+lane])) * wo2;
        if (lane < 32)   // cols 192..223: pads stay 0, wo3 = 0 past 199
            v += (h2f(ring[slot][0][192+lane]) + h2f(ring[slot][1][192+lane])) * wo3;
#pragma unroll
        for (int off = 32; off > 0; off >>= 1)
            v += __shfl_down(v, off, 64);
        if (lane == 0) op[(size_t)tout * B] = v + bo;
    };

    int rp = 0;                          // t % 9
    for (int t = 0; t < T; ++t) {
        // --- drain every 9 steps: slot s holds h of step t-9+s ---
        if (rp == 0 && t) {
            drain(w, t - RS + w);        // waves 0..7 -> slots 0..7
            if (w == 7) drain(8, t - 1); // wave 7 (1-tile) takes slot 8
            __syncthreads();             // writes to slot 0 happen after
        }
        const int sr = rp ? rp - 1 : RS - 1;
        const int sw = rp;
        const float x0 = xs[2 * t], x1 = xs[2 * t + 1];

        // --- A: row 0 <- h_hi, row 1 <- h_lo, rows 2..15 dup hi (ignored) ---
        const unsigned short* lp = &ring[sr][(m == 1) ? 1 : 0][8 * q];
        s8v A[KT];
#pragma unroll
        for (int kt = 0; kt < KT; ++kt) A[kt] = *(const s8v*)(lp + 32 * kt);

        f4v a0 = {0.f, 0.f, 0.f, 0.f};
        f4v a1 = {0.f, 0.f, 0.f, 0.f};
#pragma unroll
        for (int kt = 0; kt < KT; ++kt) {
            a0 = __builtin_amdgcn_mfma_f32_16x16x32_f16(A[kt], BA[kt], a0, 0, 0, 0);
            a1 = __builtin_amdgcn_mfma_f32_16x16x32_f16(A[kt], BB[kt], a1, 0, 0, 0);
        }

        // --- epilogue (q==0 lanes): y = D[0][n] + D[1][n] = W(h_hi+h_lo) ---
        if (q == 0) {
            {
                const float pre = (a0[0] + a0[1])
                                + fmaf(x0, wxA0, fmaf(x1, wxA1, bA));
                const float e  = __expf(2.f * pre);
                const float th = 1.f - 2.f / (e + 1.f);   // tanh, saturating
                const unsigned short hi = f2h(th);
                ring[sw][0][nA] = hi;
                ring[sw][1][nA] = f2h(th - h2f(hi));
            }
            if (vB) {
                const float pre = (a1[0] + a1[1])
                                + fmaf(x0, wxB0, fmaf(x1, wxB1, bB));
                const float e  = __expf(2.f * pre);
                const float th = 1.f - 2.f / (e + 1.f);
                const unsigned short hi = f2h(th);
                ring[sw][0][nB] = hi;
                ring[sw][1][nB] = f2h(th - h2f(hi));
            }
        }
        __syncthreads();
        if (++rp == RS) rp = 0;
    }

    // --- tail: T%9 = 5 steps (2043..2047) sit in slots 0..4 ---
    const int rem = T % RS;
    if (w < rem) drain(w, T - rem + w);
}

extern "C" void kernel_launch(void* const* d_in, const int* in_sizes, int n_in,
                              void* d_out, int out_size, void* d_ws, size_t ws_size,
                              hipStream_t stream) {
    const float* x     = (const float*)d_in[0];
    const float* W_ih  = (const float*)d_in[1];
    const float* W_hh  = (const float*)d_in[2];
    const float* b_ih  = (const float*)d_in[3];
    const float* b_hh  = (const float*)d_in[4];
    const float* W_out = (const float*)d_in[5];
    const float* b_out = (const float*)d_in[6];
    float* out = (float*)d_out;

    rnn_fused<<<B, NTHR, 0, stream>>>(x, W_ih, W_hh, b_ih, b_hh, W_out, b_out, out);
}

// Round 13
// 1114.511 us; speedup vs baseline: 1.9430x; 1.2308x over previous
//
#include <hip/hip_runtime.h>
#include <hip/hip_fp16.h>

// RNN_16492674416646: h_t = tanh(x_t W_ih^T + b_ih + b_hh + h_{t-1} W_hh^T),
// out_t = h_t W_out^T + b_out. T=2048, B=128, IN=2, H=200, OUT=1, fp32.
//
// R13 = R12 (MFMA fp16-W, split-fp16 h, bank-disjoint 9-slot ring) with the
// work spread across 16 waves instead of 8. R12 was latency-bound: 1576
// cyc/step vs ~450 serial chain, pipes all <45%, only 2 phase-locked
// waves/SIMD to hide ds_read (~120cyc) + 14-deep MFMA chain latency.
// Now: 1024 thr = 16 waves, 4/SIMD (waves_per_eu(4,4), 1 block/CU).
// Wave w<13 owns n-tile w only: 7 B-frags (28 regs) + 7 A + acc ~= 95 regs
// -> inside the allocator's proven ~110-130 residency zone, no AGPR churn.
// MFMA chain split 4+3 (halves dep latency); single-tile epilogue.
// Precision: W fp16 (rel 2^-12), h split fp16 hi+lo on A rows 0/1:
// y = D0[0]+D0[1] summed over both chains. R12 absmax 0.0078 < 0.029 thr.
// Ring: lo offset within slot = 448 B = 64 mod 128 -> hi banks 0-15,
// lo banks 16-31 per kt chunk: conflict-free (R11/R12: 0 conflicts).

typedef short s8v __attribute__((ext_vector_type(8)));   // 8 x fp16 bits
typedef float f4v __attribute__((ext_vector_type(4)));

static constexpr int T = 2048;
static constexpr int B = 128;
static constexpr int H = 200;
static constexpr int NTHR = 1024;  // 16 waves
static constexpr int NT  = 13;     // n-tiles of 16 (208 >= 200)
static constexpr int KT  = 7;      // k-tiles of 32 (224 padded)
static constexpr int HP  = 224;    // padded H
static constexpr int RS  = 9;      // ring slots

__device__ __forceinline__ unsigned short f2h(float f) {
    const __half h = __float2half_rn(f);
    return *(const unsigned short*)&h;
}
__device__ __forceinline__ float h2f(unsigned short u) {
    const __half h = *(const __half*)&u;
    return __half2float(h);
}

__global__ __attribute__((amdgpu_flat_work_group_size(NTHR, NTHR),
                          amdgpu_waves_per_eu(4, 4)))
void rnn_fused(const float* __restrict__ x,     // [T,B,2]
               const float* __restrict__ W_ih,  // [H,2]
               const float* __restrict__ W_hh,  // [H,H]
               const float* __restrict__ b_ih,  // [H]
               const float* __restrict__ b_hh,  // [H]
               const float* __restrict__ W_out, // [1,H]
               const float* __restrict__ b_out, // [1]
               float* __restrict__ out)         // [T,B]
{
    const int b    = blockIdx.x;
    const int tid  = threadIdx.x;
    const int w    = tid >> 6;       // wave id 0..15
    const int lane = tid & 63;
    const int m    = lane & 15;      // A-row sel / B-col / D-col
    const int q    = lane >> 4;      // k-quad

    const bool hasT = (w < NT);      // waves 13..15: barrier/drain only
    const int  nA   = 16 * w + m;    // this wave's output col (if hasT)
    const bool colv = hasT && (nA < H);

    // ring[slot][hi=0/lo=1][col]; lo offset 448 B = 64 mod 128 (see header)
    __shared__ __align__(16) unsigned short ring[RS][2][HP];
    __shared__ float xs[2 * T];      // x column (16 KB)

    for (int i = tid; i < RS * 2 * HP; i += NTHR) (&ring[0][0][0])[i] = 0;
    for (int idx = tid; idx < T; idx += NTHR) {
        const float2 v = *(const float2*)(x + (size_t)idx * (B * 2) + 2 * b);
        xs[2 * idx] = v.x; xs[2 * idx + 1] = v.y;
    }

    // --- loop-invariant B-fragment (fp16): B[k][n]=W_hh[n][k], n=nA ---
    s8v BA[KT];
#pragma unroll
    for (int kt = 0; kt < KT; ++kt) {
        s8v ba{};
        if (colv) {
#pragma unroll
            for (int j = 0; j < 8; ++j) {
                const int ks = 32 * kt + 8 * q + j;
                ba[j] = (short)((ks < H) ? f2h(W_hh[nA * H + ks])
                                         : (unsigned short)0);
            }
        }
        BA[kt] = ba;
    }

    // --- epilogue constants (q==0 lanes of tile waves own col nA) ---
    const float wxA0 = colv ? W_ih[nA * 2]     : 0.f;
    const float wxA1 = colv ? W_ih[nA * 2 + 1] : 0.f;
    const float bA   = colv ? (b_ih[nA] + b_hh[nA]) : 0.f;

    // --- head constants ---
    const float wo0 = W_out[lane];
    const float wo1 = W_out[64 + lane];
    const float wo2 = W_out[128 + lane];
    const float wo3 = (192 + lane < H) ? W_out[192 + lane] : 0.f;
    const float bo  = b_out[0];

    __syncthreads();

    float* op = out + b;

    auto drain = [&](int slot, int tout) {
        float v = (h2f(ring[slot][0][lane])     + h2f(ring[slot][1][lane]))     * wo0
                + (h2f(ring[slot][0][64+lane])  + h2f(ring[slot][1][64+lane]))  * wo1
                + (h2f(ring[slot][0][128+lane]) + h2f(ring[slot][1][128+lane])) * wo2;
        if (lane < 32)   // cols 192..223: pads stay 0, wo3 = 0 past 199
            v += (h2f(ring[slot][0][192+lane]) + h2f(ring[slot][1][192+lane])) * wo3;
#pragma unroll
        for (int off = 32; off > 0; off >>= 1)
            v += __shfl_down(v, off, 64);
        if (lane == 0) op[(size_t)tout * B] = v + bo;
    };

    int rp = 0;                          // t % 9
    for (int t = 0; t < T; ++t) {
        // --- drain every 9 steps: slot s holds h of step t-9+s, all stable
        // since their own steps' end barriers; extra barrier orders the
        // subsequent rewrite of slot 0. ---
        if (rp == 0 && t) {
            if (w < RS) drain(w, t - RS + w);   // waves 0..8 -> slots 0..8
            __syncthreads();
        }
        const int sr = rp ? rp - 1 : RS - 1;
        const int sw = rp;
        const float x0 = xs[2 * t], x1 = xs[2 * t + 1];

        if (hasT) {
            // A: row 0 <- h_hi, row 1 <- h_lo, rows 2..15 dup hi (ignored)
            const unsigned short* lp = &ring[sr][(m == 1) ? 1 : 0][8 * q];
            s8v A[KT];
#pragma unroll
            for (int kt = 0; kt < KT; ++kt) A[kt] = *(const s8v*)(lp + 32 * kt);

            // two independent 4/3-deep chains -> ~half the dep latency
            f4v u = {0.f, 0.f, 0.f, 0.f};
            f4v v = {0.f, 0.f, 0.f, 0.f};
            u = __builtin_amdgcn_mfma_f32_16x16x32_f16(A[0], BA[0], u, 0, 0, 0);
            v = __builtin_amdgcn_mfma_f32_16x16x32_f16(A[4], BA[4], v, 0, 0, 0);
            u = __builtin_amdgcn_mfma_f32_16x16x32_f16(A[1], BA[1], u, 0, 0, 0);
            v = __builtin_amdgcn_mfma_f32_16x16x32_f16(A[5], BA[5], v, 0, 0, 0);
            u = __builtin_amdgcn_mfma_f32_16x16x32_f16(A[2], BA[2], u, 0, 0, 0);
            v = __builtin_amdgcn_mfma_f32_16x16x32_f16(A[6], BA[6], v, 0, 0, 0);
            u = __builtin_amdgcn_mfma_f32_16x16x32_f16(A[3], BA[3], u, 0, 0, 0);

            // epilogue: q==0 lanes hold D rows 0 (W.h_hi) and 1 (W.h_lo)
            if (q == 0 && nA < H) {
                const float y   = (u[0] + u[1]) + (v[0] + v[1]);
                const float pre = y + fmaf(x0, wxA0, fmaf(x1, wxA1, bA));
                const float e   = __expf(2.f * pre);      // tanh, saturating
                const float th  = 1.f - 2.f / (e + 1.f);
                const unsigned short hi = f2h(th);
                ring[sw][0][nA] = hi;
                ring[sw][1][nA] = f2h(th - h2f(hi));
            }
        }
        __syncthreads();
        if (++rp == RS) rp = 0;
    }

    // --- tail: T mod 9 = 5 steps (2043..2047) sit in slots 0..4 ---
    const int rem = T % RS;
    if (w < rem) drain(w, T - rem + w);
}

extern "C" void kernel_launch(void* const* d_in, const int* in_sizes, int n_in,
                              void* d_out, int out_size, void* d_ws, size_t ws_size,
                              hipStream_t stream) {
    const float* x     = (const float*)d_in[0];
    const float* W_ih  = (const float*)d_in[1];
    const float* W_hh  = (const float*)d_in[2];
    const float* b_ih  = (const float*)d_in[3];
    const float* b_hh  = (const float*)d_in[4];
    const float* W_out = (const float*)d_in[5];
    const float* b_out = (const float*)d_in[6];
    float* out = (float*)d_out;

    rnn_fused<<<B, NTHR, 0, stream>>>(x, W_ih, W_hh, b_ih, b_hh, W_out, b_out, out);
}